// Round 4
// baseline (381.889 us; speedup 1.0000x reference)
//
#include <hip/hip_runtime.h>

typedef short sh8 __attribute__((ext_vector_type(8)));
typedef short sh4 __attribute__((ext_vector_type(4)));
typedef float f32x4 __attribute__((ext_vector_type(4)));

__device__ __forceinline__ short f2bf(float f) {
  unsigned u = __builtin_bit_cast(unsigned, f);
  u += 0x7fffu + ((u >> 16) & 1u);
  return (short)(u >> 16);
}

// ---------------- cast kernels ----------------
__global__ void cast_f32_bf16(const float* __restrict__ in, short* __restrict__ out, int n) {
  int i = (blockIdx.x * blockDim.x + threadIdx.x) * 4;
  if (i >= n) return;
  float4 f = *(const float4*)(in + i);
  sh4 o;
  o.x = f2bf(f.x); o.y = f2bf(f.y); o.z = f2bf(f.z); o.w = f2bf(f.w);
  *(sh4*)(out + i) = o;
}

// in: [K, Nn] fp32 row-major -> out: [Nn, K] bf16 row-major
__global__ void transpose_cast(const float* __restrict__ in, short* __restrict__ out, int K, int Nn) {
  int idx = blockIdx.x * blockDim.x + threadIdx.x;
  if (idx >= K * Nn) return;
  int k = idx / Nn;
  int n = idx - k * Nn;
  out[(size_t)n * K + k] = f2bf(in[idx]);
}

// ---------------- generic GEMM (used for proj): C[M,Nn] = A @ Bt^T + bias ----
template <int OUTF32>
__global__ __launch_bounds__(256) void gemm_bt(
    const short* __restrict__ A, const short* __restrict__ Bt,
    const float* __restrict__ bias, void* __restrict__ Cv,
    int M, int Nn, int K) {
  __shared__ short As[128][40];
  __shared__ short Bs[128][40];
  const int t = threadIdx.x;
  const int wave = t >> 6, lane = t & 63, quad = lane >> 4, l15 = lane & 15;
  const int wm = (wave >> 1) * 64, wn = (wave & 1) * 64;
  const int row0 = blockIdx.y * 128, col0 = blockIdx.x * 128;
  const int sr = t >> 2;
  const int sc = (t & 3) * 8;
  f32x4 acc[4][4] = {};
  const short* Ap = A + (size_t)(row0 + sr) * K + sc;
  const short* Bp = Bt + (size_t)(col0 + sr) * K + sc;

  for (int k0 = 0; k0 < K; k0 += 32) {
    uint4 a0 = *(const uint4*)(Ap + k0);
    uint4 a1 = *(const uint4*)(Ap + (size_t)64 * K + k0);
    uint4 b0 = *(const uint4*)(Bp + k0);
    uint4 b1 = *(const uint4*)(Bp + (size_t)64 * K + k0);
    __syncthreads();
    *(uint4*)&As[sr][sc] = a0;
    *(uint4*)&As[sr + 64][sc] = a1;
    *(uint4*)&Bs[sr][sc] = b0;
    *(uint4*)&Bs[sr + 64][sc] = b1;
    __syncthreads();
    sh8 af[4], bfv[4];
#pragma unroll
    for (int i = 0; i < 4; i++) af[i] = *(const sh8*)&As[wm + i * 16 + l15][quad * 8];
#pragma unroll
    for (int j = 0; j < 4; j++) bfv[j] = *(const sh8*)&Bs[wn + j * 16 + l15][quad * 8];
#pragma unroll
    for (int i = 0; i < 4; i++)
#pragma unroll
      for (int j = 0; j < 4; j++)
        acc[i][j] = __builtin_amdgcn_mfma_f32_16x16x32_bf16(af[i], bfv[j], acc[i][j], 0, 0, 0);
  }

#pragma unroll
  for (int i = 0; i < 4; i++)
#pragma unroll
    for (int j = 0; j < 4; j++) {
      int r = row0 + wm + i * 16 + quad * 4;
      int c = col0 + wn + j * 16 + l15;
      float bv = bias[c];
#pragma unroll
      for (int e = 0; e < 4; e++) {
        float v = acc[i][j][e] + bv;
        if (OUTF32)
          ((float*)Cv)[(size_t)(r + e) * Nn + c] = v;
        else
          ((short*)Cv)[(size_t)(r + e) * Nn + c] = f2bf(v);
      }
    }
}

// ---------------- QKV GEMM with per-head scatter ----------------
// A: xb [8192,768], Bt: wqkvT [2304,768]. Writes Qh/Kh/Vh: [48][2048][64] bf16.
// Q gets *0.125*log2(e) folded in (so attention can use raw exp2).
__global__ __launch_bounds__(256) void gemm_qkv(
    const short* __restrict__ A, const short* __restrict__ Bt,
    const float* __restrict__ bias,
    short* __restrict__ Qh, short* __restrict__ Kh, short* __restrict__ Vh) {
  const int K = 768;
  __shared__ short As[128][40];
  __shared__ short Bs[128][40];
  const int t = threadIdx.x;
  const int wave = t >> 6, lane = t & 63, quad = lane >> 4, l15 = lane & 15;
  const int wm = (wave >> 1) * 64, wn = (wave & 1) * 64;
  const int row0 = blockIdx.y * 128, col0 = blockIdx.x * 128;
  const int sr = t >> 2;
  const int sc = (t & 3) * 8;
  f32x4 acc[4][4] = {};
  const short* Ap = A + (size_t)(row0 + sr) * K + sc;
  const short* Bp = Bt + (size_t)(col0 + sr) * K + sc;

  for (int k0 = 0; k0 < K; k0 += 32) {
    uint4 a0 = *(const uint4*)(Ap + k0);
    uint4 a1 = *(const uint4*)(Ap + (size_t)64 * K + k0);
    uint4 b0 = *(const uint4*)(Bp + k0);
    uint4 b1 = *(const uint4*)(Bp + (size_t)64 * K + k0);
    __syncthreads();
    *(uint4*)&As[sr][sc] = a0;
    *(uint4*)&As[sr + 64][sc] = a1;
    *(uint4*)&Bs[sr][sc] = b0;
    *(uint4*)&Bs[sr + 64][sc] = b1;
    __syncthreads();
    sh8 af[4], bfv[4];
#pragma unroll
    for (int i = 0; i < 4; i++) af[i] = *(const sh8*)&As[wm + i * 16 + l15][quad * 8];
#pragma unroll
    for (int j = 0; j < 4; j++) bfv[j] = *(const sh8*)&Bs[wn + j * 16 + l15][quad * 8];
#pragma unroll
    for (int i = 0; i < 4; i++)
#pragma unroll
      for (int j = 0; j < 4; j++)
        acc[i][j] = __builtin_amdgcn_mfma_f32_16x16x32_bf16(af[i], bfv[j], acc[i][j], 0, 0, 0);
  }

  // s uniform per block: 768 % 128 == 0
  const int s = col0 >= 1536 ? 2 : (col0 >= 768 ? 1 : 0);
  short* dst = s == 0 ? Qh : (s == 1 ? Kh : Vh);
  const float scl = (s == 0) ? 0.125f * 1.44269504088896f : 1.0f;

#pragma unroll
  for (int j = 0; j < 4; j++) {
    int c = col0 + wn + j * 16 + l15;
    int hd = c - s * 768;
    int h = hd >> 6;
    float bv = bias[c];
#pragma unroll
    for (int i = 0; i < 4; i++) {
      int rbase = row0 + wm + i * 16 + quad * 4;
#pragma unroll
      for (int e = 0; e < 4; e++) {
        int r = rbase + e;
        int b = r >> 11, n = r & 2047;
        float v = (acc[i][j][e] + bv) * scl;
        dst[(size_t)(b * 12 + h) * 131072 + n * 64 + (hd & 63)] = f2bf(v);
      }
    }
  }
}

// ---------------- V transpose: Vh [48][2048][64] -> VhT [48][64][2048] -------
__global__ __launch_bounds__(256) void transpose_v(const short* __restrict__ Vh,
                                                   short* __restrict__ VhT) {
  __shared__ short Tl[64][72];
  const int bid = blockIdx.x;
  const int bh = bid >> 5, nt = bid & 31;
  const size_t hb = (size_t)bh * 131072;
  const int t = threadIdx.x;
  const int r0 = t >> 3;
  const int c0 = (t & 7) * 8;
  sh8 a = *(const sh8*)&Vh[hb + (size_t)(nt * 64 + r0) * 64 + c0];
  sh8 b = *(const sh8*)&Vh[hb + (size_t)(nt * 64 + r0 + 32) * 64 + c0];
#pragma unroll
  for (int j = 0; j < 8; j++) Tl[c0 + j][r0] = a[j];
#pragma unroll
  for (int j = 0; j < 8; j++) Tl[c0 + j][r0 + 32] = b[j];
  __syncthreads();
  uint4 w0 = *(const uint4*)&Tl[r0][c0];
  uint4 w1 = *(const uint4*)&Tl[r0 + 32][c0];
  *(uint4*)&VhT[hb + (size_t)r0 * 2048 + nt * 64 + c0] = w0;
  *(uint4*)&VhT[hb + (size_t)(r0 + 32) * 2048 + nt * 64 + c0] = w1;
}

// ---------------- flash attention v3: no LDS, S^T trick ----------------
// Qh/Kh: [48][2048][64] (Q pre-scaled by 0.125*log2e), VhT: [48][64][2048].
// Block = 2 waves x 64 q-rows. S^T = MFMA(A=K, B=Q) leaves P in exactly the
// A-fragment layout of 16x16x16 MFMA -> PV with zero data movement.
__global__ __launch_bounds__(128) void attn3(const short* __restrict__ Qh,
                                             const short* __restrict__ Kh,
                                             const short* __restrict__ VhT,
                                             short* __restrict__ outb) {
  const int bid = blockIdx.x;
  const int qb = bid / 48;          // 0..15
  const int bh = bid - qb * 48;     // 48 % 8 == 0: all qb of a bh on one XCD
  const int t = threadIdx.x;
  const int wave = t >> 6, lane = t & 63, quad = lane >> 4, l15 = lane & 15;
  const size_t hb = (size_t)bh * 131072;
  const int qbase = qb * 128 + wave * 64;

  // Q fragments (B-operand layout, same bytes as A-layout): 64 q-rows/wave
  sh8 qa[4][2];
#pragma unroll
  for (int qt = 0; qt < 4; qt++) {
    const short* qp = Qh + hb + (size_t)(qbase + qt * 16 + l15) * 64;
    qa[qt][0] = *(const sh8*)(qp + quad * 8);
    qa[qt][1] = *(const sh8*)(qp + 32 + quad * 8);
  }

  f32x4 o[4][4] = {};                     // [qt][dt], D-layout: row=qrow, col=d
  float lsum[4] = {0.f, 0.f, 0.f, 0.f};   // per-lane partial for qrow=l15

  const short* kb = Kh + hb;
  const short* vb = VhT + hb;

  for (int kt = 0; kt < 32; kt++) {
#pragma unroll
    for (int tk = 0; tk < 4; tk++) {
      const int key16 = kt * 64 + tk * 16;
      const short* kp = kb + (size_t)(key16 + l15) * 64 + quad * 8;
      sh8 kf0 = *(const sh8*)kp;          // K[key16+l15][quad*8..+7]
      sh8 kf1 = *(const sh8*)(kp + 32);
      sh4 pf[4];
#pragma unroll
      for (int qt = 0; qt < 4; qt++) {
        f32x4 z = {};
        // S^T tile: A=K (m=key), B=Q^T (n=qrow)
        z = __builtin_amdgcn_mfma_f32_16x16x32_bf16(kf0, qa[qt][0], z, 0, 0, 0);
        z = __builtin_amdgcn_mfma_f32_16x16x32_bf16(kf1, qa[qt][1], z, 0, 0, 0);
        // lane holds S^T[key=quad*4+r][qrow=l15]; exp2 (scale pre-folded)
        f32x4 e;
#pragma unroll
        for (int r = 0; r < 4; r++) e[r] = exp2f(z[r]);
        lsum[qt] += e[0] + e[1] + e[2] + e[3];
        sh4 p;
#pragma unroll
        for (int r = 0; r < 4; r++) p[r] = f2bf(e[r]);
        pf[qt] = p;                       // == A-frag of 16x16x16: [m=l15][k=quad*4+r]
      }
#pragma unroll
      for (int dt = 0; dt < 4; dt++) {
        // B-frag: V[key16+quad*4+j][dt*16+l15] from VhT, 4 consecutive shorts
        sh4 vf = *(const sh4*)(vb + (size_t)(dt * 16 + l15) * 2048 + key16 + quad * 4);
#pragma unroll
        for (int qt = 0; qt < 4; qt++)
          o[qt][dt] = __builtin_amdgcn_mfma_f32_16x16x16bf16_1k(pf[qt], vf, o[qt][dt], 0, 0, 0);
      }
    }
  }

  // reduce lsum across the 4 quads (lane's partial is for qrow = l15)
#pragma unroll
  for (int qt = 0; qt < 4; qt++) {
    float v = lsum[qt];
    v += __shfl_xor(v, 16, 64);
    v += __shfl_xor(v, 32, 64);
    lsum[qt] = v;                        // lanes 0..15 (and replicas) hold row totals
  }

  const int b = bh / 12, h = bh - b * 12;
#pragma unroll
  for (int qt = 0; qt < 4; qt++)
#pragma unroll
    for (int r = 0; r < 4; r++) {
      float L = __shfl(lsum[qt], quad * 4 + r, 64);
      float inv = 1.f / L;
      int n = qbase + qt * 16 + quad * 4 + r;
      short* op = outb + (size_t)(b * 2048 + n) * 768 + h * 64 + l15;
#pragma unroll
      for (int dt = 0; dt < 4; dt++) op[dt * 16] = f2bf(o[qt][dt][r] * inv);
    }
}

// ---------------- launcher ----------------
extern "C" void kernel_launch(void* const* d_in, const int* in_sizes, int n_in,
                              void* d_out, int out_size, void* d_ws, size_t ws_size,
                              hipStream_t stream) {
  const float* x = (const float*)d_in[0];
  const float* w_qkv = (const float*)d_in[1];
  const float* b_qkv = (const float*)d_in[2];
  const float* w_proj = (const float*)d_in[3];
  const float* b_proj = (const float*)d_in[4];
  float* out = (float*)d_out;

  char* p = (char*)d_ws;
  short* xb = (short*)p;     p += (size_t)8192 * 768 * 2;
  short* wqkvT = (short*)p;  p += (size_t)2304 * 768 * 2;
  short* wprojT = (short*)p; p += (size_t)768 * 768 * 2;
  short* Qh = (short*)p;     p += (size_t)48 * 131072 * 2;
  short* Kh = (short*)p;     p += (size_t)48 * 131072 * 2;
  short* Vh = (short*)p;     p += (size_t)48 * 131072 * 2;
  short* attnb = (short*)p;  p += (size_t)8192 * 768 * 2;
  short* VhT = xb;  // alias: xb dead after gemm_qkv; VhT written after

  cast_f32_bf16<<<(8192 * 768 / 4) / 256, 256, 0, stream>>>(x, xb, 8192 * 768);
  transpose_cast<<<(768 * 2304 + 255) / 256, 256, 0, stream>>>(w_qkv, wqkvT, 768, 2304);
  transpose_cast<<<(768 * 768 + 255) / 256, 256, 0, stream>>>(w_proj, wprojT, 768, 768);

  dim3 g1(2304 / 128, 8192 / 128);
  gemm_qkv<<<g1, 256, 0, stream>>>(xb, wqkvT, b_qkv, Qh, Kh, Vh);

  transpose_v<<<48 * 32, 256, 0, stream>>>(Vh, VhT);

  attn3<<<16 * 48, 128, 0, stream>>>(Qh, Kh, VhT, attnb);

  dim3 g2(768 / 128, 8192 / 128);
  gemm_bt<1><<<g2, 256, 0, stream>>>(attnb, wprojT, b_proj, out, 8192, 768, 768);
}

// Round 5
// 285.310 us; speedup vs baseline: 1.3385x; 1.3385x over previous
//
#include <hip/hip_runtime.h>

typedef short sh8 __attribute__((ext_vector_type(8)));
typedef short sh4 __attribute__((ext_vector_type(4)));
typedef float f32x4 __attribute__((ext_vector_type(4)));

__device__ __forceinline__ short f2bf(float f) {
  unsigned u = __builtin_bit_cast(unsigned, f);
  u += 0x7fffu + ((u >> 16) & 1u);
  return (short)(u >> 16);
}

// ---------------- cast kernels ----------------
__global__ void cast_f32_bf16(const float* __restrict__ in, short* __restrict__ out, int n) {
  int i = (blockIdx.x * blockDim.x + threadIdx.x) * 4;
  if (i >= n) return;
  float4 f = *(const float4*)(in + i);
  sh4 o;
  o.x = f2bf(f.x); o.y = f2bf(f.y); o.z = f2bf(f.z); o.w = f2bf(f.w);
  *(sh4*)(out + i) = o;
}

// in: [K, Nn] fp32 row-major -> out: [Nn, K] bf16 row-major
__global__ void transpose_cast(const float* __restrict__ in, short* __restrict__ out, int K, int Nn) {
  int idx = blockIdx.x * blockDim.x + threadIdx.x;
  if (idx >= K * Nn) return;
  int k = idx / Nn;
  int n = idx - k * Nn;
  out[(size_t)n * K + k] = f2bf(in[idx]);
}

// ---------------- generic GEMM (used for proj): C[M,Nn] = A @ Bt^T + bias ----
template <int OUTF32>
__global__ __launch_bounds__(256) void gemm_bt(
    const short* __restrict__ A, const short* __restrict__ Bt,
    const float* __restrict__ bias, void* __restrict__ Cv,
    int M, int Nn, int K) {
  __shared__ short As[128][40];
  __shared__ short Bs[128][40];
  const int t = threadIdx.x;
  const int wave = t >> 6, lane = t & 63, quad = lane >> 4, l15 = lane & 15;
  const int wm = (wave >> 1) * 64, wn = (wave & 1) * 64;
  const int row0 = blockIdx.y * 128, col0 = blockIdx.x * 128;
  const int sr = t >> 2;
  const int sc = (t & 3) * 8;
  f32x4 acc[4][4] = {};
  const short* Ap = A + (size_t)(row0 + sr) * K + sc;
  const short* Bp = Bt + (size_t)(col0 + sr) * K + sc;

  for (int k0 = 0; k0 < K; k0 += 32) {
    uint4 a0 = *(const uint4*)(Ap + k0);
    uint4 a1 = *(const uint4*)(Ap + (size_t)64 * K + k0);
    uint4 b0 = *(const uint4*)(Bp + k0);
    uint4 b1 = *(const uint4*)(Bp + (size_t)64 * K + k0);
    __syncthreads();
    *(uint4*)&As[sr][sc] = a0;
    *(uint4*)&As[sr + 64][sc] = a1;
    *(uint4*)&Bs[sr][sc] = b0;
    *(uint4*)&Bs[sr + 64][sc] = b1;
    __syncthreads();
    sh8 af[4], bfv[4];
#pragma unroll
    for (int i = 0; i < 4; i++) af[i] = *(const sh8*)&As[wm + i * 16 + l15][quad * 8];
#pragma unroll
    for (int j = 0; j < 4; j++) bfv[j] = *(const sh8*)&Bs[wn + j * 16 + l15][quad * 8];
#pragma unroll
    for (int i = 0; i < 4; i++)
#pragma unroll
      for (int j = 0; j < 4; j++)
        acc[i][j] = __builtin_amdgcn_mfma_f32_16x16x32_bf16(af[i], bfv[j], acc[i][j], 0, 0, 0);
  }

#pragma unroll
  for (int i = 0; i < 4; i++)
#pragma unroll
    for (int j = 0; j < 4; j++) {
      int r = row0 + wm + i * 16 + quad * 4;
      int c = col0 + wn + j * 16 + l15;
      float bv = bias[c];
#pragma unroll
      for (int e = 0; e < 4; e++) {
        float v = acc[i][j][e] + bv;
        if (OUTF32)
          ((float*)Cv)[(size_t)(r + e) * Nn + c] = v;
        else
          ((short*)Cv)[(size_t)(r + e) * Nn + c] = f2bf(v);
      }
    }
}

// ---------------- QKV GEMM with per-head scatter ----------------
// A: xb [8192,768], Bt: wqkvT [2304,768]. Writes Qh/Kh/Vh: [48][2048][64] bf16.
// Q gets *0.125*log2(e) folded in (so attention can use raw exp2).
__global__ __launch_bounds__(256) void gemm_qkv(
    const short* __restrict__ A, const short* __restrict__ Bt,
    const float* __restrict__ bias,
    short* __restrict__ Qh, short* __restrict__ Kh, short* __restrict__ Vh) {
  const int K = 768;
  __shared__ short As[128][40];
  __shared__ short Bs[128][40];
  const int t = threadIdx.x;
  const int wave = t >> 6, lane = t & 63, quad = lane >> 4, l15 = lane & 15;
  const int wm = (wave >> 1) * 64, wn = (wave & 1) * 64;
  const int row0 = blockIdx.y * 128, col0 = blockIdx.x * 128;
  const int sr = t >> 2;
  const int sc = (t & 3) * 8;
  f32x4 acc[4][4] = {};
  const short* Ap = A + (size_t)(row0 + sr) * K + sc;
  const short* Bp = Bt + (size_t)(col0 + sr) * K + sc;

  for (int k0 = 0; k0 < K; k0 += 32) {
    uint4 a0 = *(const uint4*)(Ap + k0);
    uint4 a1 = *(const uint4*)(Ap + (size_t)64 * K + k0);
    uint4 b0 = *(const uint4*)(Bp + k0);
    uint4 b1 = *(const uint4*)(Bp + (size_t)64 * K + k0);
    __syncthreads();
    *(uint4*)&As[sr][sc] = a0;
    *(uint4*)&As[sr + 64][sc] = a1;
    *(uint4*)&Bs[sr][sc] = b0;
    *(uint4*)&Bs[sr + 64][sc] = b1;
    __syncthreads();
    sh8 af[4], bfv[4];
#pragma unroll
    for (int i = 0; i < 4; i++) af[i] = *(const sh8*)&As[wm + i * 16 + l15][quad * 8];
#pragma unroll
    for (int j = 0; j < 4; j++) bfv[j] = *(const sh8*)&Bs[wn + j * 16 + l15][quad * 8];
#pragma unroll
    for (int i = 0; i < 4; i++)
#pragma unroll
      for (int j = 0; j < 4; j++)
        acc[i][j] = __builtin_amdgcn_mfma_f32_16x16x32_bf16(af[i], bfv[j], acc[i][j], 0, 0, 0);
  }

  // s uniform per block: 768 % 128 == 0
  const int s = col0 >= 1536 ? 2 : (col0 >= 768 ? 1 : 0);
  short* dst = s == 0 ? Qh : (s == 1 ? Kh : Vh);
  const float scl = (s == 0) ? 0.125f * 1.44269504088896f : 1.0f;

#pragma unroll
  for (int j = 0; j < 4; j++) {
    int c = col0 + wn + j * 16 + l15;
    int hd = c - s * 768;
    int h = hd >> 6;
    float bv = bias[c];
#pragma unroll
    for (int i = 0; i < 4; i++) {
      int rbase = row0 + wm + i * 16 + quad * 4;
#pragma unroll
      for (int e = 0; e < 4; e++) {
        int r = rbase + e;
        int b = r >> 11, n = r & 2047;
        float v = (acc[i][j][e] + bv) * scl;
        dst[(size_t)(b * 12 + h) * 131072 + n * 64 + (hd & 63)] = f2bf(v);
      }
    }
  }
}

// ---------------- V transpose + key-permute ----------------
// Vh [48][2048][64] -> VhTp [48][64][2048] where within each 32-key group the
// column position of key kk (0..31) is pos = ((kk&12)<<1) + (kk&3) + ((kk&16)>>2).
// This makes two consecutive 16-key S^T tiles pack directly into a 16x16x32
// A-fragment for PV (sum over keys is order-invariant).
__global__ __launch_bounds__(256) void transpose_v(const short* __restrict__ Vh,
                                                   short* __restrict__ VhT) {
  __shared__ short Tl[64][72];
  const int bid = blockIdx.x;
  const int bh = bid >> 5, nt = bid & 31;
  const size_t hb = (size_t)bh * 131072;
  const int t = threadIdx.x;
  const int r0 = t >> 3;        // key within tile, 0..31 (and +32)
  const int c0 = (t & 7) * 8;   // feature d
  const int pos = ((r0 & 12) << 1) + (r0 & 3) + ((r0 & 16) >> 2);  // r0<32
  sh8 a = *(const sh8*)&Vh[hb + (size_t)(nt * 64 + r0) * 64 + c0];
  sh8 b = *(const sh8*)&Vh[hb + (size_t)(nt * 64 + r0 + 32) * 64 + c0];
#pragma unroll
  for (int j = 0; j < 8; j++) Tl[c0 + j][pos] = a[j];
#pragma unroll
  for (int j = 0; j < 8; j++) Tl[c0 + j][pos + 32] = b[j];
  __syncthreads();
  uint4 w0 = *(const uint4*)&Tl[r0][c0];
  uint4 w1 = *(const uint4*)&Tl[r0 + 32][c0];
  *(uint4*)&VhT[hb + (size_t)r0 * 2048 + nt * 64 + c0] = w0;
  *(uint4*)&VhT[hb + (size_t)(r0 + 32) * 2048 + nt * 64 + c0] = w1;
}

// ---------------- flash attention v4: LDS-staged K/V + register P ----------
// Qh/Kh: [48][2048][64] (Q pre-scaled by 0.125*log2e), VhTp: [48][64][2048]
// (key-permuted). Block = 4 waves x 32 q-rows = 128 q-rows of one bh.
// S^T = MFMA(A=K, B=Q): lane holds keys quad*4+r for qrow=l15 -> after exp,
// two 16-key tiles pack into one 16x16x32 A-frag; PV at full K=32 rate.
__global__ __launch_bounds__(256) void attn4(const short* __restrict__ Qh,
                                             const short* __restrict__ Kh,
                                             const short* __restrict__ VhTp,
                                             short* __restrict__ outb) {
  const int bid = blockIdx.x;
  const int qb = bid / 48;          // 0..15
  const int bh = bid - qb * 48;     // 48 % 8 == 0: all qb of a bh on one XCD
  const int t = threadIdx.x;
  const int wave = t >> 6, lane = t & 63, quad = lane >> 4, l15 = lane & 15;
  const size_t hb = (size_t)bh * 131072;
  const int qbase = qb * 128 + wave * 32;

  __shared__ short Kl[64][72];      // [key][feat]
  __shared__ short Vt[64][72];      // [d][key-pos] (permuted)

  // Q fragments (B-operand layout): 32 q-rows per wave (qt=0,1)
  sh8 qa[2][2];
#pragma unroll
  for (int qt = 0; qt < 2; qt++) {
    const short* qp = Qh + hb + (size_t)(qbase + qt * 16 + l15) * 64;
    qa[qt][0] = *(const sh8*)(qp + quad * 8);
    qa[qt][1] = *(const sh8*)(qp + 32 + quad * 8);
  }

  f32x4 o[2][4] = {};                 // [qt][dt]; D: row=qrow(quad*4+r), col=d(l15)
  float lsum[2] = {0.f, 0.f};         // per-lane partial for qrow = l15

  const int r0 = t >> 3;              // 0..31
  const int c0 = (t & 7) * 8;         // 0..56
  const short* kbase = Kh + hb + (size_t)r0 * 64 + c0;
  const short* vbase = VhTp + hb + (size_t)r0 * 2048 + c0;

  for (int kt = 0; kt < 32; kt++) {
    const int key0 = kt * 64;
    sh8 ka = *(const sh8*)(kbase + (size_t)key0 * 64);
    sh8 kb_ = *(const sh8*)(kbase + (size_t)(key0 + 32) * 64);
    sh8 va = *(const sh8*)(vbase + key0);
    sh8 vb_ = *(const sh8*)(vbase + (size_t)32 * 2048 + key0);
    __syncthreads();
    *(sh8*)&Kl[r0][c0] = ka;
    *(sh8*)&Kl[r0 + 32][c0] = kb_;
    *(sh8*)&Vt[r0][c0] = va;
    *(sh8*)&Vt[r0 + 32][c0] = vb_;
    __syncthreads();

#pragma unroll
    for (int g = 0; g < 2; g++) {     // two 32-key groups
      sh4 ph[2][2];                   // [qt][tt]
#pragma unroll
      for (int tt = 0; tt < 2; tt++) {
        const int tk = g * 2 + tt;
        sh8 kf0 = *(const sh8*)&Kl[tk * 16 + l15][quad * 8];
        sh8 kf1 = *(const sh8*)&Kl[tk * 16 + l15][32 + quad * 8];
#pragma unroll
        for (int qt = 0; qt < 2; qt++) {
          f32x4 z = {};
          z = __builtin_amdgcn_mfma_f32_16x16x32_bf16(kf0, qa[qt][0], z, 0, 0, 0);
          z = __builtin_amdgcn_mfma_f32_16x16x32_bf16(kf1, qa[qt][1], z, 0, 0, 0);
          f32x4 e;
#pragma unroll
          for (int r = 0; r < 4; r++) e[r] = exp2f(z[r]);
          lsum[qt] += e[0] + e[1] + e[2] + e[3];
          sh4 p;
#pragma unroll
          for (int r = 0; r < 4; r++) p[r] = f2bf(e[r]);
          ph[qt][tt] = p;
        }
      }
      // pack A-frags: j<4 -> tile tt=0, j>=4 -> tt=1 (matches V permutation)
      sh8 pf[2];
#pragma unroll
      for (int qt = 0; qt < 2; qt++) {
        sh8 f;
#pragma unroll
        for (int r = 0; r < 4; r++) { f[r] = ph[qt][0][r]; f[r + 4] = ph[qt][1][r]; }
        pf[qt] = f;
      }
#pragma unroll
      for (int dt = 0; dt < 4; dt++) {
        sh8 vf = *(const sh8*)&Vt[dt * 16 + l15][g * 32 + quad * 8];
#pragma unroll
        for (int qt = 0; qt < 2; qt++)
          o[qt][dt] = __builtin_amdgcn_mfma_f32_16x16x32_bf16(pf[qt], vf, o[qt][dt], 0, 0, 0);
      }
    }
  }

  // reduce lsum across quads (lane's partial is for qrow = l15)
#pragma unroll
  for (int qt = 0; qt < 2; qt++) {
    float v = lsum[qt];
    v += __shfl_xor(v, 16, 64);
    v += __shfl_xor(v, 32, 64);
    lsum[qt] = v;
  }

  const int b = bh / 12, h = bh - b * 12;
#pragma unroll
  for (int qt = 0; qt < 2; qt++)
#pragma unroll
    for (int r = 0; r < 4; r++) {
      float L = __shfl(lsum[qt], quad * 4 + r, 64);
      float inv = 1.f / L;
      int n = qbase + qt * 16 + quad * 4 + r;
      short* op = outb + (size_t)(b * 2048 + n) * 768 + h * 64 + l15;
#pragma unroll
      for (int dt = 0; dt < 4; dt++) op[dt * 16] = f2bf(o[qt][dt][r] * inv);
    }
}

// ---------------- launcher ----------------
extern "C" void kernel_launch(void* const* d_in, const int* in_sizes, int n_in,
                              void* d_out, int out_size, void* d_ws, size_t ws_size,
                              hipStream_t stream) {
  const float* x = (const float*)d_in[0];
  const float* w_qkv = (const float*)d_in[1];
  const float* b_qkv = (const float*)d_in[2];
  const float* w_proj = (const float*)d_in[3];
  const float* b_proj = (const float*)d_in[4];
  float* out = (float*)d_out;

  char* p = (char*)d_ws;
  short* xb = (short*)p;     p += (size_t)8192 * 768 * 2;
  short* wqkvT = (short*)p;  p += (size_t)2304 * 768 * 2;
  short* wprojT = (short*)p; p += (size_t)768 * 768 * 2;
  short* Qh = (short*)p;     p += (size_t)48 * 131072 * 2;
  short* Kh = (short*)p;     p += (size_t)48 * 131072 * 2;
  short* Vh = (short*)p;     p += (size_t)48 * 131072 * 2;
  short* attnb = (short*)p;  p += (size_t)8192 * 768 * 2;
  short* VhTp = xb;  // alias: xb dead after gemm_qkv; VhTp written after

  cast_f32_bf16<<<(8192 * 768 / 4) / 256, 256, 0, stream>>>(x, xb, 8192 * 768);
  transpose_cast<<<(768 * 2304 + 255) / 256, 256, 0, stream>>>(w_qkv, wqkvT, 768, 2304);
  transpose_cast<<<(768 * 768 + 255) / 256, 256, 0, stream>>>(w_proj, wprojT, 768, 768);

  dim3 g1(2304 / 128, 8192 / 128);
  gemm_qkv<<<g1, 256, 0, stream>>>(xb, wqkvT, b_qkv, Qh, Kh, Vh);

  transpose_v<<<48 * 32, 256, 0, stream>>>(Vh, VhTp);

  attn4<<<16 * 48, 256, 0, stream>>>(Qh, Kh, VhTp, attnb);

  dim3 g2(768 / 128, 8192 / 128);
  gemm_bt<1><<<g2, 256, 0, stream>>>(attnb, wprojT, b_proj, out, 8192, 768, 768);
}